// Round 2
// baseline (782.913 us; speedup 1.0000x reference)
//
#include <hip/hip_runtime.h>
#include <cstdint>
#include <cstddef>

#define NUNITS 128000
#define NNEG   8192
#define NROWS  8192
#define NC     1024

typedef unsigned short u16;
typedef float f32x4 __attribute__((ext_vector_type(4)));

#define SCALE_A 16.0f
#define SCALE_W 256.0f
#define INV_SCALE (1.0f / (16.0f * 256.0f))

// log(expected_count(id)) for the log-uniform (Zipfian) sampler
__device__ __forceinline__ float log_expected_count(int id) {
    float idf = (float)id;
    float p = (logf(idf + 2.0f) - logf(idf + 1.0f)) / logf((float)NUNITS + 1.0f);
    float e = -expm1f((float)NNEG * log1pf(-p));
    return logf(e);
}

// pack 4 floats -> 4 fp8 e4m3 bytes (HW RNE + saturate; gfx950 = OCP e4m3fn)
__device__ __forceinline__ int pack_fp8x4(float x, float y, float z, float w) {
    int p = __builtin_amdgcn_cvt_pk_fp8_f32(x, y, 0, false);   // bytes 0,1
    p = __builtin_amdgcn_cvt_pk_fp8_f32(z, w, p, true);        // bytes 2,3
    return p;
}

// ---------------- K1: cast inputs -> fp8 (x16) AND true logits (fp32) ----------------
// one block per row; fuses old cast_inputs + true_logits (single pass over inputs)
__global__ void prep_a_kernel(const float* __restrict__ inputs, const int* __restrict__ targets,
                              const float* __restrict__ kern, const float* __restrict__ bias,
                              unsigned char* __restrict__ a8, float* __restrict__ truel) {
    const int row = blockIdx.x;
    const int tid = threadIdx.x;                  // 256 threads, 4 floats each
    const int t = targets[row];
    const float4 x = ((const float4*)(inputs + (size_t)row * NC))[tid];
    const float4 w = ((const float4*)(kern + (size_t)t * NC))[tid];
    ((int*)(a8 + (size_t)row * NC))[tid] =
        pack_fp8x4(x.x * SCALE_A, x.y * SCALE_A, x.z * SCALE_A, x.w * SCALE_A);
    // fp32 dot for the numerically-sensitive true logit
    float s = x.x * w.x + x.y * w.y + x.z * w.z + x.w * w.w;
    for (int m = 32; m; m >>= 1) s += __shfl_xor(s, m, 64);
    __shared__ float red[4];
    if ((tid & 63) == 0) red[tid >> 6] = s;
    __syncthreads();
    if (tid == 0)
        truel[row] = red[0] + red[1] + red[2] + red[3] + bias[t] - log_expected_count(t);
}

// ---------------- K2: gather sampled rows -> fp8 (x256) AND bcorr ----------------
__global__ void prep_w_kernel(const float* __restrict__ kern, const int* __restrict__ sampled,
                              const float* __restrict__ bias,
                              unsigned char* __restrict__ w8, float* __restrict__ bc) {
    const int srow = blockIdx.x;
    const int tid = threadIdx.x;
    const int id = sampled[srow];
    const float4 v = ((const float4*)(kern + (size_t)id * NC))[tid];
    ((int*)(w8 + (size_t)srow * NC))[tid] =
        pack_fp8x4(v.x * SCALE_W, v.y * SCALE_W, v.z * SCALE_W, v.w * SCALE_W);
    if (tid == 0) bc[srow] = bias[id] - log_expected_count(id);
}

// ---------------- K3: fp8 MFMA GEMM + fused partial sum-of-exp ----------------
// C[n][s] = (1/4096) * sum_c A8[n][c]*W8[s][c]; epilogue exp(C + bc[s]) with
// accidental-hit masking, per-row reduce, write partial[chunk][row] (coalesced).
__global__ __launch_bounds__(256, 2) void gemm_lse_kernel(
    const unsigned char* __restrict__ A8, const unsigned char* __restrict__ W8,
    const float* __restrict__ bcorr, const int* __restrict__ targets,
    const int* __restrict__ sampled, float* __restrict__ partial) {
    __shared__ unsigned char lds_A[128 * 32];   // [128 rows][32 B] fp8, BK=32
    __shared__ unsigned char lds_W[128 * 32];
    __shared__ int   lds_tgt[128];
    __shared__ int   lds_smp[128];
    __shared__ float lds_bc[128];
    __shared__ float lds_rowsum[128];

    const int tid = threadIdx.x;
    const int wv = tid >> 6;            // wave 0..3
    const int lane = tid & 63;
    const int bn0 = blockIdx.x * 128;   // S tile
    const int bm0 = blockIdx.y * 128;   // N (row) tile
    const int wm = (wv >> 1) * 64;
    const int wn = (wv & 1) * 64;

    if (tid < 128) {
        lds_tgt[tid] = targets[bm0 + tid];
        lds_smp[tid] = sampled[bn0 + tid];
        lds_bc[tid] = bcorr[bn0 + tid];
        lds_rowsum[tid] = 0.0f;
    }

    f32x4 acc[4][4];
    const f32x4 zero4 = {0.0f, 0.0f, 0.0f, 0.0f};
#pragma unroll
    for (int i = 0; i < 4; ++i)
#pragma unroll
        for (int j = 0; j < 4; ++j) acc[i][j] = zero4;

    // staging: tile = 128x32 fp8 = 4 KB = 4 chunks of 1 KB; wave wv stages chunk wv.
    // chunk = 32 rows x 32 B; lane covers row wv*32+(lane>>1), bytes (lane&1)*16..+16.
    // LDS linear dest (base + lane*16) == row-major [128][32] exactly.
    const int srow_st = wv * 32 + (lane >> 1);
    const int cb = (lane & 1) * 16;
    const int arow = lane & 15;          // fragment m/n index
    const int kq = (lane >> 4) * 8;      // fragment k byte offset (quad*8)

    for (int kt = 0; kt < NC / 32; ++kt) {
        const int k0 = kt * 32;
        const unsigned char* ga = A8 + (size_t)(bm0 + srow_st) * NC + k0 + cb;
        const unsigned char* gw = W8 + (size_t)(bn0 + srow_st) * NC + k0 + cb;
        __builtin_amdgcn_global_load_lds(
            (const __attribute__((address_space(1))) void*)ga,
            (__attribute__((address_space(3))) void*)&lds_A[wv * 1024], 16, 0, 0);
        __builtin_amdgcn_global_load_lds(
            (const __attribute__((address_space(1))) void*)gw,
            (__attribute__((address_space(3))) void*)&lds_W[wv * 1024], 16, 0, 0);
        __syncthreads();

        long af[4], bfv[4];
#pragma unroll
        for (int mt = 0; mt < 4; ++mt)
            af[mt] = *(const long*)&lds_A[(wm + mt * 16 + arow) * 32 + kq];
#pragma unroll
        for (int nt = 0; nt < 4; ++nt)
            bfv[nt] = *(const long*)&lds_W[(wn + nt * 16 + arow) * 32 + kq];
#pragma unroll
        for (int mt = 0; mt < 4; ++mt)
#pragma unroll
            for (int nt = 0; nt < 4; ++nt)
                acc[mt][nt] = __builtin_amdgcn_mfma_f32_16x16x32_fp8_fp8(
                    af[mt], bfv[nt], acc[mt][nt], 0, 0, 0);
        __syncthreads();
    }

    // C/D layout (dtype-independent): col = lane&15, row = (lane>>4)*4 + reg
#pragma unroll
    for (int mt = 0; mt < 4; ++mt) {
#pragma unroll
        for (int r = 0; r < 4; ++r) {
            const int row_l = wm + mt * 16 + (lane >> 4) * 4 + r;
            const int tg = lds_tgt[row_l];
            float s = 0.0f;
#pragma unroll
            for (int nt = 0; nt < 4; ++nt) {
                const int col_l = wn + nt * 16 + (lane & 15);
                const float logit = acc[mt][nt][r] * INV_SCALE + lds_bc[col_l];
                s += (lds_smp[col_l] == tg) ? 0.0f : __expf(logit);  // hit -> exp==0
            }
#pragma unroll
            for (int m = 1; m < 16; m <<= 1) s += __shfl_xor(s, m, 64);
            if ((lane & 15) == 0) atomicAdd(&lds_rowsum[row_l], s);
        }
    }
    __syncthreads();
    if (tid < 128)  // chunk-major: coalesced write here, coalesced read in row_lse
        partial[(size_t)blockIdx.x * NROWS + bm0 + tid] = lds_rowsum[tid];
}

// ---------------- K4: per-row logsumexp + block partial loss ----------------
__global__ void row_lse_kernel(const float* __restrict__ partial, const float* __restrict__ truel,
                               float* __restrict__ bsums) {
    const int row = blockIdx.x * 256 + threadIdx.x;    // grid 32 x 256
    float s = 0.0f;
#pragma unroll
    for (int c = 0; c < 64; ++c) s += partial[(size_t)c * NROWS + row];  // coalesced
    const float tl = truel[row];
    float v = logf(s + expf(tl)) - tl;
    for (int m = 32; m; m >>= 1) v += __shfl_xor(v, m, 64);
    __shared__ float red[4];
    if ((threadIdx.x & 63) == 0) red[threadIdx.x >> 6] = v;
    __syncthreads();
    if (threadIdx.x == 0) bsums[blockIdx.x] = red[0] + red[1] + red[2] + red[3];
}

// ---------------- K5: final mean ----------------
__global__ void finalize_kernel(const float* __restrict__ bsums, float* __restrict__ out) {
    float v = (threadIdx.x < 32) ? bsums[threadIdx.x] : 0.0f;
    for (int m = 32; m; m >>= 1) v += __shfl_xor(v, m, 64);
    if (threadIdx.x == 0) out[0] = v / (float)NROWS;
}

extern "C" void kernel_launch(void* const* d_in, const int* in_sizes, int n_in,
                              void* d_out, int out_size, void* d_ws, size_t ws_size,
                              hipStream_t stream) {
    (void)in_sizes; (void)n_in; (void)out_size; (void)ws_size;
    const float* inputs  = (const float*)d_in[0];   // [8192,1024] fp32
    const int*   targets = (const int*)d_in[1];     // [8192]
    const int*   sampled = (const int*)d_in[2];     // [8192]
    const float* kern    = (const float*)d_in[3];   // [128000,1024] fp32
    const float* bias    = (const float*)d_in[4];   // [128000]
    float* out = (float*)d_out;

    char* ws = (char*)d_ws;
    unsigned char* a8 = (unsigned char*)ws;                              // 8 MB
    unsigned char* w8 = (unsigned char*)(ws + (size_t)8  * 1024 * 1024); // 8 MB
    float* bc    = (float*)(ws + (size_t)16 * 1024 * 1024);              // 32 KB
    float* truel = (float*)(ws + (size_t)16 * 1024 * 1024 + 32768);      // 32 KB
    float* part  = (float*)(ws + (size_t)16 * 1024 * 1024 + 65536);      // 2 MB
    float* bsums = (float*)(ws + (size_t)16 * 1024 * 1024 + 65536 +
                            (size_t)64 * NROWS * 4);                     // 128 B

    prep_a_kernel<<<dim3(8192), dim3(256), 0, stream>>>(inputs, targets, kern, bias, a8, truel);
    prep_w_kernel<<<dim3(8192), dim3(256), 0, stream>>>(kern, sampled, bias, w8, bc);
    gemm_lse_kernel<<<dim3(64, 64), dim3(256), 0, stream>>>(a8, w8, bc, targets, sampled, part);
    row_lse_kernel<<<dim3(32), dim3(256), 0, stream>>>(part, truel, bsums);
    finalize_kernel<<<dim3(1), dim3(64), 0, stream>>>(bsums, out);
}